// Round 8
// baseline (474.127 us; speedup 1.0000x reference)
//
#include <hip/hip_runtime.h>
#include <math.h>

#define N_NODES 50000
#define N_EDGES 800000
#define ND 128
#define ED 16
#define H1 256
#define H2 32

typedef short bf16x8 __attribute__((ext_vector_type(8)));
typedef float f32x4 __attribute__((ext_vector_type(4)));
typedef _Float16 half2v __attribute__((ext_vector_type(2)));
typedef uint uintx4 __attribute__((ext_vector_type(4)));
typedef uint uintx8 __attribute__((ext_vector_type(8)));

// f16 dot2, f32 accumulate, ea operand in VGPR
__device__ __forceinline__ float dot2h(uint w_, uint ea_v, float c) {
    asm("v_dot2_f32_f16 %0, %1, %2, %0" : "+v"(c) : "v"(w_), "v"(ea_v));
    return c;
}
// f16 dot2, ea operand in SGPR (src0 position allows scalar)
__device__ __forceinline__ float dot2hs(uint w_, uint ea_s, float c) {
    asm("v_dot2_f32_f16 %0, %2, %1, %0" : "+v"(c) : "v"(w_), "s"(ea_s));
    return c;
}
// d = f16_lo(a) * b + c   (f32)
__device__ __forceinline__ float fmamix_lo(uint a, float b, float c) {
    float d;
    asm("v_fma_mix_f32 %0, %1, %2, %3 op_sel_hi:[1,0,0]" : "=v"(d) : "v"(a), "v"(b), "v"(c));
    return d;
}
// d = f16_hi(a) * b + c
__device__ __forceinline__ float fmamix_hi(uint a, float b, float c) {
    float d;
    asm("v_fma_mix_f32 %0, %1, %2, %3 op_sel:[1,0,0] op_sel_hi:[1,0,0]" : "=v"(d) : "v"(a), "v"(b), "v"(c));
    return d;
}
__device__ __forceinline__ ushort f2bf(float f) {
    uint u = __float_as_uint(f);
    return (ushort)((u + 0x7fff + ((u >> 16) & 1)) >> 16);
}
// 2^x via v_exp_f32
__device__ __forceinline__ float exp2a(float x) {
    float d;
    asm("v_exp_f32 %0, %1" : "=v"(d) : "v"(x));
    return d;
}
// DPP add step: v += dpp_move(v, CTRL) (invalid lanes contribute 0)
template <int CTRL, int RM, int BM>
__device__ __forceinline__ float dpp_add(float v) {
    int m = __builtin_amdgcn_update_dpp(0, __float_as_int(v), CTRL, RM, BM, true);
    return v + __int_as_float(m);
}
// full wave64 sum -> uniform (via lane 63)
__device__ __forceinline__ float wave_red64(float v) {
    v = dpp_add<0x111, 0xf, 0xf>(v);   // row_shr:1
    v = dpp_add<0x112, 0xf, 0xf>(v);   // row_shr:2
    v = dpp_add<0x114, 0xf, 0xe>(v);   // row_shr:4
    v = dpp_add<0x118, 0xf, 0xc>(v);   // row_shr:8
    v = dpp_add<0x142, 0xa, 0xf>(v);   // row_bcast:15
    v = dpp_add<0x143, 0xc, 0xf>(v);   // row_bcast:31
    return __int_as_float(__builtin_amdgcn_readlane(__float_as_int(v), 63));
}
// 32-lane sums: lane31 = sum(0..31), lane63 = sum(32..63)
__device__ __forceinline__ float half_red32(float v) {
    v = dpp_add<0x111, 0xf, 0xf>(v);
    v = dpp_add<0x112, 0xf, 0xf>(v);
    v = dpp_add<0x114, 0xf, 0xe>(v);
    v = dpp_add<0x118, 0xf, 0xc>(v);
    v = dpp_add<0x142, 0xa, 0xf>(v);
    return v;
}
__device__ __forceinline__ float rlane(float v, int l) {
    return __int_as_float(__builtin_amdgcn_readlane(__float_as_int(v), l));
}
// wave-uniform scalar loads: 4 csr slots + 4 edge-attr rows (32B each)
__device__ __forceinline__ void sload_iter(const int* pc, const char* pe,
                                           uintx4& c, uintx8& e0, uintx8& e1,
                                           uintx8& e2, uintx8& e3) {
    asm volatile("s_load_dwordx4 %0, %5, 0x0\n\t"
                 "s_load_dwordx8 %1, %6, 0x0\n\t"
                 "s_load_dwordx8 %2, %6, 0x20\n\t"
                 "s_load_dwordx8 %3, %6, 0x40\n\t"
                 "s_load_dwordx8 %4, %6, 0x60\n\t"
                 "s_waitcnt lgkmcnt(0)"
                 : "=s"(c), "=s"(e0), "=s"(e1), "=s"(e2), "=s"(e3)
                 : "s"(pc), "s"(pe));
}

// ---------------------------------------------------------------- degree counts
__global__ void k_deg(const int* __restrict__ ei, int* __restrict__ counts, int E) {
    int e = blockIdx.x * blockDim.x + threadIdx.x;
    if (e < E) atomicAdd(&counts[ei[E + e]], 1);
}

// ---------------------------------------------------------------- 3-phase scan -> rowptr (+1 self loop per node)
__global__ void k_scan1(const int* __restrict__ counts, int* __restrict__ partial, int n, int chunk) {
    __shared__ int sh[256];
    int beg = blockIdx.x * chunk, end = min(beg + chunk, n);
    int sum = 0;
    for (int i = beg + threadIdx.x; i < end; i += 256) sum += counts[i] + 1;
    sh[threadIdx.x] = sum;
    __syncthreads();
    for (int off = 128; off; off >>= 1) {
        if (threadIdx.x < off) sh[threadIdx.x] += sh[threadIdx.x + off];
        __syncthreads();
    }
    if (threadIdx.x == 0) partial[blockIdx.x] = sh[0];
}
__global__ void k_scan2(int* __restrict__ partial) {
    __shared__ int sh[256];
    int v = partial[threadIdx.x];
    sh[threadIdx.x] = v;
    __syncthreads();
    for (int off = 1; off < 256; off <<= 1) {
        int t = (threadIdx.x >= off) ? sh[threadIdx.x - off] : 0;
        __syncthreads();
        sh[threadIdx.x] += t;
        __syncthreads();
    }
    partial[threadIdx.x] = sh[threadIdx.x] - v;
}
__global__ void k_scan3(const int* __restrict__ counts, const int* __restrict__ partial,
                        int* __restrict__ rowptr, int n, int chunk) {
    __shared__ int sh[256];
    int beg = blockIdx.x * chunk, end = min(beg + chunk, n);
    int run = partial[blockIdx.x];
    for (int base = beg; base < end; base += 256) {
        int i = base + threadIdx.x;
        int v = (i < end) ? counts[i] + 1 : 0;
        sh[threadIdx.x] = v;
        __syncthreads();
        for (int off = 1; off < 256; off <<= 1) {
            int t = (threadIdx.x >= off) ? sh[threadIdx.x - off] : 0;
            __syncthreads();
            sh[threadIdx.x] += t;
            __syncthreads();
        }
        if (i < end) rowptr[i + 1] = run + sh[threadIdx.x];
        __syncthreads();
        run += sh[255];
        __syncthreads();
    }
    if (blockIdx.x == 0 && threadIdx.x == 0) rowptr[0] = 0;
}

// ---------------------------------------------------------------- fill CSR: src + ea rows (f16) in slot order
__global__ void k_fill_csr(const int* __restrict__ ei, const float* __restrict__ ea,
                           const int* __restrict__ rowptr, int* __restrict__ fill,
                           int* __restrict__ csr_src, _Float16* __restrict__ ea_h, int E, int n) {
    int idx = blockIdx.x * blockDim.x + threadIdx.x;
    if (idx < E) {
        int dst = ei[E + idx];
        int slot = rowptr[dst] + atomicAdd(&fill[dst], 1);
        csr_src[slot] = ei[idx];
        const float* srow = ea + (size_t)idx * ED;
        _Float16* drow = ea_h + (size_t)slot * ED;
        #pragma unroll
        for (int q = 0; q < 4; ++q) {
            float4 f = ((const float4*)srow)[q];
            drow[q * 4 + 0] = (_Float16)f.x;
            drow[q * 4 + 1] = (_Float16)f.y;
            drow[q * 4 + 2] = (_Float16)f.z;
            drow[q * 4 + 3] = (_Float16)f.w;
        }
    } else if (idx < E + n) {
        int i = idx - E;
        csr_src[rowptr[i + 1] - 1] = i;  // self loop in last slot
    }
}

// ---------------------------------------------------------------- self-loop attr row = mean (wave per node, coalesced)
__global__ __launch_bounds__(256) void k_loop_mean(_Float16* __restrict__ ea_h,
                                                   const int* __restrict__ rowptr, int n) {
    int lane = threadIdx.x & 63;
    int wave = (blockIdx.x * blockDim.x + threadIdx.x) >> 6;
    int nwaves = (gridDim.x * blockDim.x) >> 6;
    int g = lane >> 3, q = lane & 7;
    for (int node = wave; node < n; node += nwaves) {
        int beg = rowptr[node], last = rowptr[node + 1] - 1;
        float sx = 0.f, sy = 0.f;
        for (int r = beg + g; r < last; r += 8) {
            uint v = *(const uint*)((const char*)ea_h + ((uint)r << 5) + (q << 2));
            half2v h = __builtin_bit_cast(half2v, v);
            sx += (float)h.x;
            sy += (float)h.y;
        }
        #pragma unroll
        for (int off = 8; off <= 32; off <<= 1) {
            sx += __shfl_xor(sx, off);
            sy += __shfl_xor(sy, off);
        }
        if (lane < 8) {
            int cnt = last - beg;
            float inv = 1.f / (float)(cnt > 0 ? cnt : 1);
            half2v o;
            o.x = (_Float16)(sx * inv);
            o.y = (_Float16)(sy * inv);
            *(uint*)((char*)ea_h + ((uint)last << 5) + (q << 2)) = __builtin_bit_cast(uint, o);
        }
    }
}

// ---------------------------------------------------------------- one fused pack kernel
__global__ __launch_bounds__(256) void k_pack_all(const float* __restrict__ x,
                                                  const float* __restrict__ Wl1,
                                                  const float* __restrict__ Wr1,
                                                  const float* __restrict__ We1,
                                                  const float* __restrict__ Wl2,
                                                  const float* __restrict__ Wr2,
                                                  const float* __restrict__ We2,
                                                  ushort* __restrict__ x_bf,
                                                  ushort* __restrict__ wcat1,
                                                  ushort* __restrict__ wcat2,
                                                  _Float16* __restrict__ We1_h,
                                                  _Float16* __restrict__ We2_h) {
    const int T4 = N_NODES * ND / 4;
    int idx = blockIdx.x * blockDim.x + threadIdx.x;
    if (idx < T4) {
        float4 f = ((const float4*)x)[idx];
        ushort4 o;
        o.x = f2bf(f.x); o.y = f2bf(f.y); o.z = f2bf(f.z); o.w = f2bf(f.w);
        ((ushort4*)x_bf)[idx] = o;
        return;
    }
    int k = idx - T4;
    if (k < 2 * H1 * ND) {
        int row = k / ND, kk = k - row * ND;
        float v = (row < H1) ? Wl1[(size_t)row * ND + kk] : Wr1[(size_t)(row - H1) * ND + kk];
        wcat1[k] = f2bf(v);
        return;
    }
    k -= 2 * H1 * ND;
    if (k < 2 * H2 * H1) {
        int row = k / H1, kk = k - row * H1;
        float v = (row < H2) ? Wl2[(size_t)row * H1 + kk] : Wr2[(size_t)(row - H2) * H1 + kk];
        wcat2[k] = f2bf(v);
        return;
    }
    k -= 2 * H2 * H1;
    if (k < H1 * ED) { We1_h[k] = (_Float16)We1[k]; return; }
    k -= H1 * ED;
    if (k < H2 * ED) We2_h[k] = (_Float16)We2[k];
}

// ---------------------------------------------------------------- MFMA GEMM: Y = X(bf16) @ Wcat(bf16)^T + bias
template <int HALF_A, int HALF_B>
__global__ __launch_bounds__(256) void k_gemm_mfma(const ushort* __restrict__ Xb,
                                                   const ushort* __restrict__ Wc,
                                                   const float* __restrict__ ba,
                                                   const float* __restrict__ bb,
                                                   void* __restrict__ Ya,
                                                   void* __restrict__ Yb,
                                                   int n, int K, int C) {
    int tid = threadIdx.x;
    int lane = tid & 63, wv = tid >> 6;
    int r = lane & 15, kg = lane >> 4;
    int row0 = blockIdx.x * 64 + wv * 16;
    int colblk = blockIdx.y * 64;
    int arow = row0 + r;
    if (arow >= n) arow = n - 1;
    const ushort* aptr = Xb + (size_t)arow * K + kg * 8;
    f32x4 acc[4] = {};
    for (int k0 = 0; k0 < K; k0 += 32) {
        bf16x8 av = *(const bf16x8*)(aptr + k0);
        #pragma unroll
        for (int t = 0; t < 4; ++t) {
            const ushort* bptr = Wc + (size_t)(colblk + t * 16 + r) * K + k0 + kg * 8;
            bf16x8 bv = *(const bf16x8*)bptr;
            acc[t] = __builtin_amdgcn_mfma_f32_16x16x32_bf16(av, bv, acc[t], 0, 0, 0);
        }
    }
    #pragma unroll
    for (int t = 0; t < 4; ++t) {
        int col = colblk + t * 16 + r;
        int rowb = row0 + kg * 4;
        #pragma unroll
        for (int q = 0; q < 4; ++q) {
            int row = rowb + q;
            if (row >= n) continue;
            float v = acc[t][q];
            if (col < C) {
                v += ba[col];
                if (HALF_A) ((_Float16*)Ya)[(size_t)row * C + col] = (_Float16)v;
                else        ((float*)Ya)[(size_t)row * C + col] = v;
            } else {
                v += bb[col - C];
                if (HALF_B) ((_Float16*)Yb)[(size_t)row * C + (col - C)] = (_Float16)v;
                else        ((float*)Yb)[(size_t)row * C + (col - C)] = v;
            }
        }
    }
}

// ---------------------------------------------------------------- per-edge logit, ea in SGPRs
__device__ __forceinline__ float logit_s(const uint (&w)[4][8], const uint* es,
                                         uint2 xv, float4 xrv, float4 a06, float4 a04) {
    float we0 = 0.f, we1 = 0.f, we2 = 0.f, we3 = 0.f;
    #pragma unroll
    for (int q = 0; q < 8; ++q) {
        we0 = dot2hs(w[0][q], es[q], we0);
        we1 = dot2hs(w[1][q], es[q], we1);
        we2 = dot2hs(w[2][q], es[q], we2);
        we3 = dot2hs(w[3][q], es[q], we3);
    }
    float z0 = fmamix_lo(xv.x, 1.0f, we0 + xrv.x);
    float z1 = fmamix_hi(xv.x, 1.0f, we1 + xrv.y);
    float z2 = fmamix_lo(xv.y, 1.0f, we2 + xrv.z);
    float z3 = fmamix_hi(xv.y, 1.0f, we3 + xrv.w);
    return fmaf(a06.x, z0, fmaf(a04.x, fabsf(z0),
           fmaf(a06.y, z1, fmaf(a04.y, fabsf(z1),
           fmaf(a06.z, z2, fmaf(a04.z, fabsf(z2),
           fmaf(a06.w, z3, a04.w * fabsf(z3))))))));
}
// per-edge logit, ea in VGPRs (tail path)
__device__ __forceinline__ float logit_v(const uint (&w)[4][8], uint4 e0, uint4 e1,
                                         uint2 xv, float4 xrv, float4 a06, float4 a04) {
    uint ev[8] = {e0.x, e0.y, e0.z, e0.w, e1.x, e1.y, e1.z, e1.w};
    float we0 = 0.f, we1 = 0.f, we2 = 0.f, we3 = 0.f;
    #pragma unroll
    for (int q = 0; q < 8; ++q) {
        we0 = dot2h(w[0][q], ev[q], we0);
        we1 = dot2h(w[1][q], ev[q], we1);
        we2 = dot2h(w[2][q], ev[q], we2);
        we3 = dot2h(w[3][q], ev[q], we3);
    }
    float z0 = fmamix_lo(xv.x, 1.0f, we0 + xrv.x);
    float z1 = fmamix_hi(xv.x, 1.0f, we1 + xrv.y);
    float z2 = fmamix_lo(xv.y, 1.0f, we2 + xrv.z);
    float z3 = fmamix_hi(xv.y, 1.0f, we3 + xrv.w);
    return fmaf(a06.x, z0, fmaf(a04.x, fabsf(z0),
           fmaf(a06.y, z1, fmaf(a04.y, fabsf(z1),
           fmaf(a06.z, z2, fmaf(a04.z, fabsf(z2),
           fmaf(a06.w, z3, a04.w * fabsf(z3))))))));
}

// ---------------------------------------------------------------- layer-1 fused GAT: wave/node, scalar edge data, DPP reduce
__global__ __launch_bounds__(256) void k_gat1(const _Float16* __restrict__ xlh,
                                              const _Float16* __restrict__ xrh,
                                              const _Float16* __restrict__ ea_h,
                                              const _Float16* __restrict__ We_h,
                                              const float* __restrict__ att,
                                              const float* __restrict__ bias,
                                              const int* __restrict__ rowptr,
                                              const int* __restrict__ csr_src,
                                              ushort* __restrict__ out_bf, int n) {
    const int lane = threadIdx.x & 63;
    int wave = (blockIdx.x * blockDim.x + threadIdx.x) >> 6;
    int nwaves = (gridDim.x * blockDim.x) >> 6;
    const uint* Wp = (const uint*)We_h;
    uint w[4][8];
    #pragma unroll
    for (int r = 0; r < 4; ++r)
        #pragma unroll
        for (int q = 0; q < 8; ++q) w[r][q] = Wp[(lane * 4 + r) * 8 + q];
    const float L2E = 1.44269504088896f;   // log2(e): fold exp->exp2
    float4 attv = ((const float4*)att)[lane];
    float4 bv = ((const float4*)bias)[lane];
    float4 a06, a04;
    a06.x = 0.6f * L2E * attv.x; a06.y = 0.6f * L2E * attv.y;
    a06.z = 0.6f * L2E * attv.z; a06.w = 0.6f * L2E * attv.w;
    a04.x = 0.4f * L2E * attv.x; a04.y = 0.4f * L2E * attv.y;
    a04.z = 0.4f * L2E * attv.z; a04.w = 0.4f * L2E * attv.w;
    const uint laneoff = (uint)lane << 3;

    for (int node = wave; node < n; node += nwaves) {
        uint2 xru = *(const uint2*)((const char*)xrh + ((size_t)node << 9) + laneoff);
        half2v xr0 = __builtin_bit_cast(half2v, xru.x);
        half2v xr1 = __builtin_bit_cast(half2v, xru.y);
        float4 xrv;
        xrv.x = (float)xr0.x; xrv.y = (float)xr0.y;
        xrv.z = (float)xr1.x; xrv.w = (float)xr1.y;
        int beg = rowptr[node], end = rowptr[node + 1];
        float denom = 0.f, ac0 = 0.f, ac1 = 0.f, ac2 = 0.f, ac3 = 0.f;
        int j = beg;
        for (; j + 3 < end; j += 4) {
            int ju = __builtin_amdgcn_readfirstlane(j);
            uintx4 cs;
            uintx8 ea0, ea1, ea2, ea3;
            sload_iter(csr_src + ju, (const char*)ea_h + ((size_t)ju << 5), cs, ea0, ea1, ea2, ea3);
            uint s0 = cs[0], s1 = cs[1], s2 = cs[2], s3 = cs[3];
            uint2 x0 = *(const uint2*)((const char*)xlh + ((size_t)s0 << 9) + laneoff);
            uint2 x1 = *(const uint2*)((const char*)xlh + ((size_t)s1 << 9) + laneoff);
            uint2 x2 = *(const uint2*)((const char*)xlh + ((size_t)s2 << 9) + laneoff);
            uint2 x3 = *(const uint2*)((const char*)xlh + ((size_t)s3 << 9) + laneoff);
            uint eA[8], eB[8], eC[8], eD[8];
            #pragma unroll
            for (int q = 0; q < 8; ++q) { eA[q] = ea0[q]; eB[q] = ea1[q]; eC[q] = ea2[q]; eD[q] = ea3[q]; }
            float p0 = logit_s(w, eA, x0, xrv, a06, a04);
            float p1 = logit_s(w, eB, x1, xrv, a06, a04);
            float p2 = logit_s(w, eC, x2, xrv, a06, a04);
            float p3 = logit_s(w, eD, x3, xrv, a06, a04);
            float q0 = exp2a(wave_red64(p0));
            float q1 = exp2a(wave_red64(p1));
            float q2 = exp2a(wave_red64(p2));
            float q3 = exp2a(wave_red64(p3));
            denom += (q0 + q1) + (q2 + q3);
            ac0 = fmamix_lo(x0.x, q0, ac0); ac1 = fmamix_hi(x0.x, q0, ac1);
            ac2 = fmamix_lo(x0.y, q0, ac2); ac3 = fmamix_hi(x0.y, q0, ac3);
            ac0 = fmamix_lo(x1.x, q1, ac0); ac1 = fmamix_hi(x1.x, q1, ac1);
            ac2 = fmamix_lo(x1.y, q1, ac2); ac3 = fmamix_hi(x1.y, q1, ac3);
            ac0 = fmamix_lo(x2.x, q2, ac0); ac1 = fmamix_hi(x2.x, q2, ac1);
            ac2 = fmamix_lo(x2.y, q2, ac2); ac3 = fmamix_hi(x2.y, q2, ac3);
            ac0 = fmamix_lo(x3.x, q3, ac0); ac1 = fmamix_hi(x3.x, q3, ac1);
            ac2 = fmamix_lo(x3.y, q3, ac2); ac3 = fmamix_hi(x3.y, q3, ac3);
        }
        for (; j < end; ++j) {
            int s0 = __builtin_amdgcn_readfirstlane(csr_src[j]);
            const uint4* eP = (const uint4*)((const char*)ea_h + ((size_t)(uint)j << 5));
            uint4 e00 = eP[0], e01 = eP[1];
            uint2 x0 = *(const uint2*)((const char*)xlh + ((size_t)(uint)s0 << 9) + laneoff);
            float p0 = logit_v(w, e00, e01, x0, xrv, a06, a04);
            float q0 = exp2a(wave_red64(p0));
            denom += q0;
            ac0 = fmamix_lo(x0.x, q0, ac0); ac1 = fmamix_hi(x0.x, q0, ac1);
            ac2 = fmamix_lo(x0.y, q0, ac2); ac3 = fmamix_hi(x0.y, q0, ac3);
        }
        float inv = 1.f / denom;
        ushort4 o;
        o.x = f2bf(fmaf(ac0, inv, bv.x));
        o.y = f2bf(fmaf(ac1, inv, bv.y));
        o.z = f2bf(fmaf(ac2, inv, bv.z));
        o.w = f2bf(fmaf(ac3, inv, bv.w));
        *(ushort4*)(out_bf + ((size_t)node << 8) + (lane << 2)) = o;
    }
}

// ---------------------------------------------------------------- layer-2 fused GAT: wave/node, halves = 2 edges, DPP reduce
__global__ __launch_bounds__(256) void k_gat2(const float* __restrict__ xl,
                                              const float* __restrict__ xr,
                                              const _Float16* __restrict__ ea_h,
                                              const _Float16* __restrict__ We_h,
                                              const float* __restrict__ att,
                                              const float* __restrict__ bias,
                                              const int* __restrict__ rowptr,
                                              const int* __restrict__ csr_src,
                                              float* __restrict__ out, int n) {
    int tid = threadIdx.x;
    int lane = tid & 63;
    int sub = lane >> 5, c = lane & 31;
    int wave = (blockIdx.x * blockDim.x + tid) >> 6;
    int nwaves = (gridDim.x * blockDim.x) >> 6;
    const uint* Wp = (const uint*)We_h;
    uint w0 = Wp[c * 8 + 0], w1 = Wp[c * 8 + 1], w2 = Wp[c * 8 + 2], w3 = Wp[c * 8 + 3];
    uint w4 = Wp[c * 8 + 4], w5 = Wp[c * 8 + 5], w6 = Wp[c * 8 + 6], w7 = Wp[c * 8 + 7];
    const float L2E = 1.44269504088896f;
    float attc = att[c];
    float a06 = 0.6f * L2E * attc, a04 = 0.4f * L2E * attc;
    float bc = bias[c];
    bool hi = sub != 0;

    for (int node = wave; node < n; node += nwaves) {
        float xrc = xr[((size_t)node << 5) + c];
        int beg = rowptr[node], end = rowptr[node + 1];
        float denom = 0.f, acc = 0.f;
        int j = beg;
        for (; j + 3 < end; j += 4) {
            int jA = j + sub, jB = j + 2 + sub;
            int sA = csr_src[jA], sB = csr_src[jB];
            const uint4* ePA = (const uint4*)((const char*)ea_h + ((uint)jA << 5));
            const uint4* ePB = (const uint4*)((const char*)ea_h + ((uint)jB << 5));
            uint4 a0 = ePA[0], a1 = ePA[1];
            uint4 b0 = ePB[0], b1 = ePB[1];
            float xlA = *(const float*)((const char*)xl + (((uint)sA << 7) + (c << 2)));
            float xlB = *(const float*)((const char*)xl + (((uint)sB << 7) + (c << 2)));
            float weA = dot2h(w7, a1.w, dot2h(w6, a1.z, dot2h(w5, a1.y, dot2h(w4, a1.x,
                        dot2h(w3, a0.w, dot2h(w2, a0.z, dot2h(w1, a0.y, dot2h(w0, a0.x, 0.f))))))));
            float weB = dot2h(w7, b1.w, dot2h(w6, b1.z, dot2h(w5, b1.y, dot2h(w4, b1.x,
                        dot2h(w3, b0.w, dot2h(w2, b0.z, dot2h(w1, b0.y, dot2h(w0, b0.x, 0.f))))))));
            float zA = xlA + xrc + weA;
            float zB = xlB + xrc + weB;
            float pA = fmaf(a06, zA, a04 * fabsf(zA));
            float pB = fmaf(a06, zB, a04 * fabsf(zB));
            pA = half_red32(pA);
            pB = half_red32(pB);
            float tA = hi ? rlane(pA, 63) : rlane(pA, 31);
            float tB = hi ? rlane(pB, 63) : rlane(pB, 31);
            float qA = exp2a(tA), qB = exp2a(tB);
            denom += qA + qB;
            acc = fmaf(qA, xlA, fmaf(qB, xlB, acc));
        }
        for (; j < end; j += 2) {
            int jj = j + sub;
            bool act = jj < end;
            int js = act ? jj : j;
            int s = csr_src[js];
            const uint4* eP = (const uint4*)((const char*)ea_h + ((uint)js << 5));
            uint4 e0 = eP[0], e1 = eP[1];
            float xlv = *(const float*)((const char*)xl + (((uint)s << 7) + (c << 2)));
            float we = dot2h(w7, e1.w, dot2h(w6, e1.z, dot2h(w5, e1.y, dot2h(w4, e1.x,
                       dot2h(w3, e0.w, dot2h(w2, e0.z, dot2h(w1, e0.y, dot2h(w0, e0.x, 0.f))))))));
            float z = xlv + xrc + we;
            float p = fmaf(a06, z, a04 * fabsf(z));
            p = half_red32(p);
            float t = hi ? rlane(p, 63) : rlane(p, 31);
            float pe = act ? exp2a(t) : 0.f;
            denom += pe;
            acc = fmaf(pe, xlv, acc);
        }
        acc += __shfl_xor(acc, 32);
        denom += __shfl_xor(denom, 32);
        if (sub == 0) out[((size_t)node << 5) + c] = acc / denom + bc;
    }
}

// ---------------------------------------------------------------- mean over nodes
__global__ __launch_bounds__(256) void k_mean(const float* __restrict__ h2,
                                              float* __restrict__ out, int total, float invN) {
    __shared__ float red[H2];
    int tid = threadIdx.x;
    if (tid < H2) red[tid] = 0.f;
    __syncthreads();
    float part = 0.f;
    for (int idx = blockIdx.x * blockDim.x + tid; idx < total; idx += gridDim.x * blockDim.x)
        part += h2[idx];
    atomicAdd(&red[tid & 31], part);
    __syncthreads();
    if (tid < H2) atomicAdd(&out[tid], red[tid] * invN);
}

// ----------------------------------------------------------------
extern "C" void kernel_launch(void* const* d_in, const int* in_sizes, int n_in,
                              void* d_out, int out_size, void* d_ws, size_t ws_size,
                              hipStream_t stream) {
    const float* x   = (const float*)d_in[0];
    const int*   ei  = (const int*)d_in[1];
    const float* ea  = (const float*)d_in[2];
    const float* Wl1 = (const float*)d_in[3];
    const float* bl1 = (const float*)d_in[4];
    const float* Wr1 = (const float*)d_in[5];
    const float* br1 = (const float*)d_in[6];
    const float* We1 = (const float*)d_in[7];
    const float* at1 = (const float*)d_in[8];
    const float* bi1 = (const float*)d_in[9];
    const float* Wl2 = (const float*)d_in[10];
    const float* bl2 = (const float*)d_in[11];
    const float* Wr2 = (const float*)d_in[12];
    const float* br2 = (const float*)d_in[13];
    const float* We2 = (const float*)d_in[14];
    const float* at2 = (const float*)d_in[15];
    const float* bi2 = (const float*)d_in[16];
    float* out = (float*)d_out;

    const int N = N_NODES, E = N_EDGES, ET = N_EDGES + N_NODES;
    const int SCAN_CHUNK = (N + 255) / 256;

    size_t off = 0;
    auto carve = [&](size_t bytes) {
        void* p = (char*)d_ws + off;
        off += (bytes + 255) & ~(size_t)255;
        return p;
    };
    int*      counts  = (int*)carve((size_t)N * 4);
    int*      fill    = (int*)carve((size_t)N * 4);
    int*      rowptr  = (int*)carve((size_t)(N + 1) * 4);
    int*      partial = (int*)carve(256 * 4);
    int*      csr_src = (int*)carve((size_t)ET * 4);
    _Float16* ea_h    = (_Float16*)carve((size_t)ET * ED * 2);
    _Float16* We1_h   = (_Float16*)carve((size_t)H1 * ED * 2);
    _Float16* We2_h   = (_Float16*)carve((size_t)H2 * ED * 2);
    ushort*   x_bf    = (ushort*)carve((size_t)N * ND * 2);
    ushort*   wcat1   = (ushort*)carve((size_t)2 * H1 * ND * 2);
    ushort*   wcat2   = (ushort*)carve((size_t)2 * H2 * H1 * 2);
    _Float16* xl1h    = (_Float16*)carve((size_t)N * H1 * 2);
    _Float16* xr1h    = (_Float16*)carve((size_t)N * H1 * 2);
    ushort*   h1_bf   = (ushort*)carve((size_t)N * H1 * 2);
    float*    xl2     = (float*)carve((size_t)N * H2 * 4);
    float*    xr2     = (float*)carve((size_t)N * H2 * 4);
    float*    h2      = (float*)carve((size_t)N * H2 * 4);

    // counts and fill are adjacent -> single memset over both
    size_t zspan = (size_t)((char*)fill - (char*)counts) + (size_t)N * 4;
    hipMemsetAsync(counts, 0, zspan, stream);
    hipMemsetAsync(out, 0, (size_t)H2 * 4, stream);

    k_deg<<<(E + 255) / 256, 256, 0, stream>>>(ei, counts, E);
    k_scan1<<<256, 256, 0, stream>>>(counts, partial, N, SCAN_CHUNK);
    k_scan2<<<1, 256, 0, stream>>>(partial);
    k_scan3<<<256, 256, 0, stream>>>(counts, partial, rowptr, N, SCAN_CHUNK);
    k_fill_csr<<<(E + N + 255) / 256, 256, 0, stream>>>(ei, ea, rowptr, fill, csr_src, ea_h, E, N);
    k_loop_mean<<<1024, 256, 0, stream>>>(ea_h, rowptr, N);

    const int T4 = N_NODES * ND / 4;
    const int TS = 2 * H1 * ND + 2 * H2 * H1 + H1 * ED + H2 * ED;
    k_pack_all<<<(T4 + TS + 255) / 256, 256, 0, stream>>>(x, Wl1, Wr1, We1, Wl2, Wr2, We2,
                                                          x_bf, wcat1, wcat2, We1_h, We2_h);

    // layer 1: GEMM -> xl1h, xr1h (both f16); fused GAT -> h1 (bf16)
    k_gemm_mfma<1, 1><<<dim3((N + 63) / 64, (2 * H1) / 64), 256, 0, stream>>>(
        x_bf, wcat1, bl1, br1, (void*)xl1h, (void*)xr1h, N, ND, H1);
    k_gat1<<<4096, 256, 0, stream>>>(xl1h, xr1h, ea_h, We1_h, at1, bi1,
                                     rowptr, csr_src, h1_bf, N);

    // layer 2
    k_gemm_mfma<0, 0><<<dim3((N + 63) / 64, (2 * H2) / 64), 256, 0, stream>>>(
        h1_bf, wcat2, bl2, br2, (void*)xl2, (void*)xr2, N, H1, H2);
    k_gat2<<<12500, 256, 0, stream>>>(xl2, xr2, ea_h, We2_h, at2, bi2,
                                      rowptr, csr_src, h2, N);

    k_mean<<<128, 256, 0, stream>>>(h2, out, N * H2, 1.0f / (float)N);
}

// Round 11
// 427.586 us; speedup vs baseline: 1.1088x; 1.1088x over previous
//
#include <hip/hip_runtime.h>
#include <math.h>

#define N_NODES 50000
#define N_EDGES 800000
#define ND 128
#define ED 16
#define H1 256
#define H2 32

typedef short bf16x8 __attribute__((ext_vector_type(8)));
typedef float f32x4 __attribute__((ext_vector_type(4)));
typedef _Float16 half2v __attribute__((ext_vector_type(2)));
typedef uint uintx4 __attribute__((ext_vector_type(4)));
typedef uint uintx8 __attribute__((ext_vector_type(8)));

// f16 dot2, f32 accumulate, ea operand in VGPR
__device__ __forceinline__ float dot2h(uint w_, uint ea_v, float c) {
    asm("v_dot2_f32_f16 %0, %1, %2, %0" : "+v"(c) : "v"(w_), "v"(ea_v));
    return c;
}
// f16 dot2, ea operand in SGPR (src0 position allows scalar)
__device__ __forceinline__ float dot2hs(uint w_, uint ea_s, float c) {
    asm("v_dot2_f32_f16 %0, %2, %1, %0" : "+v"(c) : "v"(w_), "s"(ea_s));
    return c;
}
// d = f16_lo(a) * b + c   (f32)
__device__ __forceinline__ float fmamix_lo(uint a, float b, float c) {
    float d;
    asm("v_fma_mix_f32 %0, %1, %2, %3 op_sel_hi:[1,0,0]" : "=v"(d) : "v"(a), "v"(b), "v"(c));
    return d;
}
// d = f16_hi(a) * b + c
__device__ __forceinline__ float fmamix_hi(uint a, float b, float c) {
    float d;
    asm("v_fma_mix_f32 %0, %1, %2, %3 op_sel:[1,0,0] op_sel_hi:[1,0,0]" : "=v"(d) : "v"(a), "v"(b), "v"(c));
    return d;
}
__device__ __forceinline__ ushort f2bf(float f) {
    uint u = __float_as_uint(f);
    return (ushort)((u + 0x7fff + ((u >> 16) & 1)) >> 16);
}
// 2^x via v_exp_f32
__device__ __forceinline__ float exp2a(float x) {
    float d;
    asm("v_exp_f32 %0, %1" : "=v"(d) : "v"(x));
    return d;
}

// wave-uniform scalar loads, DRAINED inside the asm (safe: outputs complete at
// asm end, consumed within the same iteration). 8 edges: 8 csr + 8 ea rows.
__device__ __forceinline__ void sload8(const int* pc, const char* pe,
                                       uintx4& c0, uintx4& c1,
                                       uintx8& e0, uintx8& e1, uintx8& e2, uintx8& e3,
                                       uintx8& e4, uintx8& e5, uintx8& e6, uintx8& e7) {
    asm volatile("s_load_dwordx4 %0, %10, 0x0\n\t"
                 "s_load_dwordx4 %1, %10, 0x10\n\t"
                 "s_load_dwordx8 %2, %11, 0x0\n\t"
                 "s_load_dwordx8 %3, %11, 0x20\n\t"
                 "s_load_dwordx8 %4, %11, 0x40\n\t"
                 "s_load_dwordx8 %5, %11, 0x60\n\t"
                 "s_load_dwordx8 %6, %11, 0x80\n\t"
                 "s_load_dwordx8 %7, %11, 0xa0\n\t"
                 "s_load_dwordx8 %8, %11, 0xc0\n\t"
                 "s_load_dwordx8 %9, %11, 0xe0\n\t"
                 "s_waitcnt lgkmcnt(0)"
                 : "=s"(c0), "=s"(c1), "=s"(e0), "=s"(e1), "=s"(e2), "=s"(e3),
                   "=s"(e4), "=s"(e5), "=s"(e6), "=s"(e7)
                 : "s"(pc), "s"(pe));
}
// 4-edge variant (mid tail)
__device__ __forceinline__ void sload4(const int* pc, const char* pe,
                                       uintx4& c, uintx8& e0, uintx8& e1,
                                       uintx8& e2, uintx8& e3) {
    asm volatile("s_load_dwordx4 %0, %5, 0x0\n\t"
                 "s_load_dwordx8 %1, %6, 0x0\n\t"
                 "s_load_dwordx8 %2, %6, 0x20\n\t"
                 "s_load_dwordx8 %3, %6, 0x40\n\t"
                 "s_load_dwordx8 %4, %6, 0x60\n\t"
                 "s_waitcnt lgkmcnt(0)"
                 : "=s"(c), "=s"(e0), "=s"(e1), "=s"(e2), "=s"(e3)
                 : "s"(pc), "s"(pe));
}

__device__ __forceinline__ uint2 ldx(const _Float16* xlh, uint s, uint laneoff) {
    return *(const uint2*)((const char*)xlh + ((size_t)s << 9) + laneoff);
}
__device__ __forceinline__ int rfl(int v) { return __builtin_amdgcn_readfirstlane(v); }

// ---------------------------------------------------------------- degree counts
__global__ void k_deg(const int* __restrict__ ei, int* __restrict__ counts, int E) {
    int e = blockIdx.x * blockDim.x + threadIdx.x;
    if (e < E) atomicAdd(&counts[ei[E + e]], 1);
}

// ---------------------------------------------------------------- 3-phase scan -> rowptr (+1 self loop per node)
__global__ void k_scan1(const int* __restrict__ counts, int* __restrict__ partial, int n, int chunk) {
    __shared__ int sh[256];
    int beg = blockIdx.x * chunk, end = min(beg + chunk, n);
    int sum = 0;
    for (int i = beg + threadIdx.x; i < end; i += 256) sum += counts[i] + 1;
    sh[threadIdx.x] = sum;
    __syncthreads();
    for (int off = 128; off; off >>= 1) {
        if (threadIdx.x < off) sh[threadIdx.x] += sh[threadIdx.x + off];
        __syncthreads();
    }
    if (threadIdx.x == 0) partial[blockIdx.x] = sh[0];
}
__global__ void k_scan2(int* __restrict__ partial) {
    __shared__ int sh[256];
    int v = partial[threadIdx.x];
    sh[threadIdx.x] = v;
    __syncthreads();
    for (int off = 1; off < 256; off <<= 1) {
        int t = (threadIdx.x >= off) ? sh[threadIdx.x - off] : 0;
        __syncthreads();
        sh[threadIdx.x] += t;
        __syncthreads();
    }
    partial[threadIdx.x] = sh[threadIdx.x] - v;
}
__global__ void k_scan3(const int* __restrict__ counts, const int* __restrict__ partial,
                        int* __restrict__ rowptr, int n, int chunk) {
    __shared__ int sh[256];
    int beg = blockIdx.x * chunk, end = min(beg + chunk, n);
    int run = partial[blockIdx.x];
    for (int base = beg; base < end; base += 256) {
        int i = base + threadIdx.x;
        int v = (i < end) ? counts[i] + 1 : 0;
        sh[threadIdx.x] = v;
        __syncthreads();
        for (int off = 1; off < 256; off <<= 1) {
            int t = (threadIdx.x >= off) ? sh[threadIdx.x - off] : 0;
            __syncthreads();
            sh[threadIdx.x] += t;
            __syncthreads();
        }
        if (i < end) rowptr[i + 1] = run + sh[threadIdx.x];
        __syncthreads();
        run += sh[255];
        __syncthreads();
    }
    if (blockIdx.x == 0 && threadIdx.x == 0) rowptr[0] = 0;
}

// ---------------------------------------------------------------- fill CSR: src + ea rows (f16) in slot order
__global__ void k_fill_csr(const int* __restrict__ ei, const float* __restrict__ ea,
                           const int* __restrict__ rowptr, int* __restrict__ fill,
                           int* __restrict__ csr_src, _Float16* __restrict__ ea_h, int E, int n) {
    int idx = blockIdx.x * blockDim.x + threadIdx.x;
    if (idx < E) {
        int dst = ei[E + idx];
        int slot = rowptr[dst] + atomicAdd(&fill[dst], 1);
        csr_src[slot] = ei[idx];
        const float* srow = ea + (size_t)idx * ED;
        _Float16* drow = ea_h + (size_t)slot * ED;
        #pragma unroll
        for (int q = 0; q < 4; ++q) {
            float4 f = ((const float4*)srow)[q];
            drow[q * 4 + 0] = (_Float16)f.x;
            drow[q * 4 + 1] = (_Float16)f.y;
            drow[q * 4 + 2] = (_Float16)f.z;
            drow[q * 4 + 3] = (_Float16)f.w;
        }
    } else if (idx < E + n) {
        int i = idx - E;
        csr_src[rowptr[i + 1] - 1] = i;  // self loop in last slot
    }
}

// ---------------------------------------------------------------- self-loop attr row = mean (wave per node, coalesced)
__global__ __launch_bounds__(256) void k_loop_mean(_Float16* __restrict__ ea_h,
                                                   const int* __restrict__ rowptr, int n) {
    int lane = threadIdx.x & 63;
    int wave = (blockIdx.x * blockDim.x + threadIdx.x) >> 6;
    int nwaves = (gridDim.x * blockDim.x) >> 6;
    int g = lane >> 3, q = lane & 7;
    for (int node = wave; node < n; node += nwaves) {
        int beg = rowptr[node], last = rowptr[node + 1] - 1;
        float sx = 0.f, sy = 0.f;
        for (int r = beg + g; r < last; r += 8) {
            uint v = *(const uint*)((const char*)ea_h + ((uint)r << 5) + (q << 2));
            half2v h = __builtin_bit_cast(half2v, v);
            sx += (float)h.x;
            sy += (float)h.y;
        }
        #pragma unroll
        for (int off = 8; off <= 32; off <<= 1) {
            sx += __shfl_xor(sx, off);
            sy += __shfl_xor(sy, off);
        }
        if (lane < 8) {
            int cnt = last - beg;
            float inv = 1.f / (float)(cnt > 0 ? cnt : 1);
            half2v o;
            o.x = (_Float16)(sx * inv);
            o.y = (_Float16)(sy * inv);
            *(uint*)((char*)ea_h + ((uint)last << 5) + (q << 2)) = __builtin_bit_cast(uint, o);
        }
    }
}

// ---------------------------------------------------------------- one fused pack kernel
__global__ __launch_bounds__(256) void k_pack_all(const float* __restrict__ x,
                                                  const float* __restrict__ Wl1,
                                                  const float* __restrict__ Wr1,
                                                  const float* __restrict__ We1,
                                                  const float* __restrict__ Wl2,
                                                  const float* __restrict__ Wr2,
                                                  const float* __restrict__ We2,
                                                  ushort* __restrict__ x_bf,
                                                  ushort* __restrict__ wcat1,
                                                  ushort* __restrict__ wcat2,
                                                  _Float16* __restrict__ We1_h,
                                                  _Float16* __restrict__ We2_h) {
    const int T4 = N_NODES * ND / 4;
    int idx = blockIdx.x * blockDim.x + threadIdx.x;
    if (idx < T4) {
        float4 f = ((const float4*)x)[idx];
        ushort4 o;
        o.x = f2bf(f.x); o.y = f2bf(f.y); o.z = f2bf(f.z); o.w = f2bf(f.w);
        ((ushort4*)x_bf)[idx] = o;
        return;
    }
    int k = idx - T4;
    if (k < 2 * H1 * ND) {
        int row = k / ND, kk = k - row * ND;
        float v = (row < H1) ? Wl1[(size_t)row * ND + kk] : Wr1[(size_t)(row - H1) * ND + kk];
        wcat1[k] = f2bf(v);
        return;
    }
    k -= 2 * H1 * ND;
    if (k < 2 * H2 * H1) {
        int row = k / H1, kk = k - row * H1;
        float v = (row < H2) ? Wl2[(size_t)row * H1 + kk] : Wr2[(size_t)(row - H2) * H1 + kk];
        wcat2[k] = f2bf(v);
        return;
    }
    k -= 2 * H2 * H1;
    if (k < H1 * ED) { We1_h[k] = (_Float16)We1[k]; return; }
    k -= H1 * ED;
    if (k < H2 * ED) We2_h[k] = (_Float16)We2[k];
}

// ---------------------------------------------------------------- MFMA GEMM: Y = X(bf16) @ Wcat(bf16)^T + bias
template <int HALF_A, int HALF_B>
__global__ __launch_bounds__(256) void k_gemm_mfma(const ushort* __restrict__ Xb,
                                                   const ushort* __restrict__ Wc,
                                                   const float* __restrict__ ba,
                                                   const float* __restrict__ bb,
                                                   void* __restrict__ Ya,
                                                   void* __restrict__ Yb,
                                                   int n, int K, int C) {
    int tid = threadIdx.x;
    int lane = tid & 63, wv = tid >> 6;
    int r = lane & 15, kg = lane >> 4;
    int row0 = blockIdx.x * 64 + wv * 16;
    int colblk = blockIdx.y * 64;
    int arow = row0 + r;
    if (arow >= n) arow = n - 1;
    const ushort* aptr = Xb + (size_t)arow * K + kg * 8;
    f32x4 acc[4] = {};
    for (int k0 = 0; k0 < K; k0 += 32) {
        bf16x8 av = *(const bf16x8*)(aptr + k0);
        #pragma unroll
        for (int t = 0; t < 4; ++t) {
            const ushort* bptr = Wc + (size_t)(colblk + t * 16 + r) * K + k0 + kg * 8;
            bf16x8 bv = *(const bf16x8*)bptr;
            acc[t] = __builtin_amdgcn_mfma_f32_16x16x32_bf16(av, bv, acc[t], 0, 0, 0);
        }
    }
    #pragma unroll
    for (int t = 0; t < 4; ++t) {
        int col = colblk + t * 16 + r;
        int rowb = row0 + kg * 4;
        #pragma unroll
        for (int q = 0; q < 4; ++q) {
            int row = rowb + q;
            if (row >= n) continue;
            float v = acc[t][q];
            if (col < C) {
                v += ba[col];
                if (HALF_A) ((_Float16*)Ya)[(size_t)row * C + col] = (_Float16)v;
                else        ((float*)Ya)[(size_t)row * C + col] = v;
            } else {
                v += bb[col - C];
                if (HALF_B) ((_Float16*)Yb)[(size_t)row * C + (col - C)] = (_Float16)v;
                else        ((float*)Yb)[(size_t)row * C + (col - C)] = v;
            }
        }
    }
}

// ---------------------------------------------------------------- per-edge logit, ea in SGPRs
__device__ __forceinline__ float logit_s(const uint (&w)[4][8], uintx8 es,
                                         uint2 xv, float4 xrv, float4 a06, float4 a04) {
    float we0 = 0.f, we1 = 0.f, we2 = 0.f, we3 = 0.f;
    #pragma unroll
    for (int q = 0; q < 8; ++q) {
        we0 = dot2hs(w[0][q], es[q], we0);
        we1 = dot2hs(w[1][q], es[q], we1);
        we2 = dot2hs(w[2][q], es[q], we2);
        we3 = dot2hs(w[3][q], es[q], we3);
    }
    float z0 = fmamix_lo(xv.x, 1.0f, we0 + xrv.x);
    float z1 = fmamix_hi(xv.x, 1.0f, we1 + xrv.y);
    float z2 = fmamix_lo(xv.y, 1.0f, we2 + xrv.z);
    float z3 = fmamix_hi(xv.y, 1.0f, we3 + xrv.w);
    return fmaf(a06.x, z0, fmaf(a04.x, fabsf(z0),
           fmaf(a06.y, z1, fmaf(a04.y, fabsf(z1),
           fmaf(a06.z, z2, fmaf(a04.z, fabsf(z2),
           fmaf(a06.w, z3, a04.w * fabsf(z3))))))));
}
// per-edge logit, ea in VGPRs (tail path)
__device__ __forceinline__ float logit_v(const uint (&w)[4][8], uint4 e0, uint4 e1,
                                         uint2 xv, float4 xrv, float4 a06, float4 a04) {
    uint ev[8] = {e0.x, e0.y, e0.z, e0.w, e1.x, e1.y, e1.z, e1.w};
    float we0 = 0.f, we1 = 0.f, we2 = 0.f, we3 = 0.f;
    #pragma unroll
    for (int q = 0; q < 8; ++q) {
        we0 = dot2h(w[0][q], ev[q], we0);
        we1 = dot2h(w[1][q], ev[q], we1);
        we2 = dot2h(w[2][q], ev[q], we2);
        we3 = dot2h(w[3][q], ev[q], we3);
    }
    float z0 = fmamix_lo(xv.x, 1.0f, we0 + xrv.x);
    float z1 = fmamix_hi(xv.x, 1.0f, we1 + xrv.y);
    float z2 = fmamix_lo(xv.y, 1.0f, we2 + xrv.z);
    float z3 = fmamix_hi(xv.y, 1.0f, we3 + xrv.w);
    return fmaf(a06.x, z0, fmaf(a04.x, fabsf(z0),
           fmaf(a06.y, z1, fmaf(a04.y, fabsf(z1),
           fmaf(a06.z, z2, fmaf(a04.z, fabsf(z2),
           fmaf(a06.w, z3, a04.w * fabsf(z3))))))));
}

#define ACC1(X, Q)                                              \
    ac0 = fmamix_lo((X).x, (Q), ac0);                           \
    ac1 = fmamix_hi((X).x, (Q), ac1);                           \
    ac2 = fmamix_lo((X).y, (Q), ac2);                           \
    ac3 = fmamix_hi((X).y, (Q), ac3);

// ---------------------------------------------------------------- layer-1 fused GAT: wave/node, 8-edge SMEM batches
__global__ __launch_bounds__(256) void k_gat1(const _Float16* __restrict__ xlh,
                                              const _Float16* __restrict__ xrh,
                                              const _Float16* __restrict__ ea_h,
                                              const _Float16* __restrict__ We_h,
                                              const float* __restrict__ att,
                                              const float* __restrict__ bias,
                                              const int* __restrict__ rowptr,
                                              const int* __restrict__ csr_src,
                                              ushort* __restrict__ out_bf, int n) {
    const int lane = threadIdx.x & 63;
    int wave = rfl((int)((blockIdx.x * blockDim.x + threadIdx.x) >> 6));
    int nwaves = (gridDim.x * blockDim.x) >> 6;
    const uint* Wp = (const uint*)We_h;
    uint w[4][8];
    #pragma unroll
    for (int r = 0; r < 4; ++r)
        #pragma unroll
        for (int q = 0; q < 8; ++q) w[r][q] = Wp[(lane * 4 + r) * 8 + q];
    const float L2E = 1.44269504088896f;   // fold exp -> exp2
    float4 attv = ((const float4*)att)[lane];
    float4 bv = ((const float4*)bias)[lane];
    float4 a06, a04;
    a06.x = 0.6f * L2E * attv.x; a06.y = 0.6f * L2E * attv.y;
    a06.z = 0.6f * L2E * attv.z; a06.w = 0.6f * L2E * attv.w;
    a04.x = 0.4f * L2E * attv.x; a04.y = 0.4f * L2E * attv.y;
    a04.z = 0.4f * L2E * attv.z; a04.w = 0.4f * L2E * attv.w;
    const uint laneoff = (uint)lane << 3;
    const char* eab = (const char*)ea_h;

    for (int node = wave; node < n; node += nwaves) {
        uint2 xru = *(const uint2*)((const char*)xrh + ((size_t)node << 9) + laneoff);
        half2v xr0 = __builtin_bit_cast(half2v, xru.x);
        half2v xr1 = __builtin_bit_cast(half2v, xru.y);
        float4 xrv;
        xrv.x = (float)xr0.x; xrv.y = (float)xr0.y;
        xrv.z = (float)xr1.x; xrv.w = (float)xr1.y;
        int beg = rfl(rowptr[node]), end = rfl(rowptr[node + 1]);
        float denom = 0.f, ac0 = 0.f, ac1 = 0.f, ac2 = 0.f, ac3 = 0.f;
        int j = beg;
        // ---- 8-edge batches: one SMEM drain per 8 edges ----
        for (; j + 7 < end; j += 8) {
            uintx4 c0, c1;
            uintx8 e0, e1, e2, e3, e4, e5, e6, e7;
            sload8(csr_src + j, eab + ((size_t)j << 5), c0, c1, e0, e1, e2, e3, e4, e5, e6, e7);
            uint2 x0 = ldx(xlh, c0[0], laneoff);
            uint2 x1 = ldx(xlh, c0[1], laneoff);
            uint2 x2 = ldx(xlh, c0[2], laneoff);
            uint2 x3 = ldx(xlh, c0[3], laneoff);
            uint2 x4 = ldx(xlh, c1[0], laneoff);
            uint2 x5 = ldx(xlh, c1[1], laneoff);
            uint2 x6 = ldx(xlh, c1[2], laneoff);
            uint2 x7 = ldx(xlh, c1[3], laneoff);
            float p0 = logit_s(w, e0, x0, xrv, a06, a04);
            float p1 = logit_s(w, e1, x1, xrv, a06, a04);
            float p2 = logit_s(w, e2, x2, xrv, a06, a04);
            float p3 = logit_s(w, e3, x3, xrv, a06, a04);
            float p4 = logit_s(w, e4, x4, xrv, a06, a04);
            float p5 = logit_s(w, e5, x5, xrv, a06, a04);
            float p6 = logit_s(w, e6, x6, xrv, a06, a04);
            float p7 = logit_s(w, e7, x7, xrv, a06, a04);
            #pragma unroll
            for (int off = 32; off >= 1; off >>= 1) {
                p0 += __shfl_xor(p0, off); p1 += __shfl_xor(p1, off);
                p2 += __shfl_xor(p2, off); p3 += __shfl_xor(p3, off);
                p4 += __shfl_xor(p4, off); p5 += __shfl_xor(p5, off);
                p6 += __shfl_xor(p6, off); p7 += __shfl_xor(p7, off);
            }
            float q0 = exp2a(p0), q1 = exp2a(p1), q2 = exp2a(p2), q3 = exp2a(p3);
            float q4 = exp2a(p4), q5 = exp2a(p5), q6 = exp2a(p6), q7 = exp2a(p7);
            denom += ((q0 + q1) + (q2 + q3)) + ((q4 + q5) + (q6 + q7));
            ACC1(x0, q0) ACC1(x1, q1) ACC1(x2, q2) ACC1(x3, q3)
            ACC1(x4, q4) ACC1(x5, q5) ACC1(x6, q6) ACC1(x7, q7)
        }
        // ---- one optional 4-edge batch ----
        if (j + 3 < end) {
            uintx4 c0;
            uintx8 e0, e1, e2, e3;
            sload4(csr_src + j, eab + ((size_t)j << 5), c0, e0, e1, e2, e3);
            uint2 x0 = ldx(xlh, c0[0], laneoff);
            uint2 x1 = ldx(xlh, c0[1], laneoff);
            uint2 x2 = ldx(xlh, c0[2], laneoff);
            uint2 x3 = ldx(xlh, c0[3], laneoff);
            float p0 = logit_s(w, e0, x0, xrv, a06, a04);
            float p1 = logit_s(w, e1, x1, xrv, a06, a04);
            float p2 = logit_s(w, e2, x2, xrv, a06, a04);
            float p3 = logit_s(w, e3, x3, xrv, a06, a04);
            #pragma unroll
            for (int off = 32; off >= 1; off >>= 1) {
                p0 += __shfl_xor(p0, off); p1 += __shfl_xor(p1, off);
                p2 += __shfl_xor(p2, off); p3 += __shfl_xor(p3, off);
            }
            float q0 = exp2a(p0), q1 = exp2a(p1), q2 = exp2a(p2), q3 = exp2a(p3);
            denom += (q0 + q1) + (q2 + q3);
            ACC1(x0, q0) ACC1(x1, q1) ACC1(x2, q2) ACC1(x3, q3)
            j += 4;
        }
        // ---- scalar tail (0-3 edges) ----
        for (; j < end; ++j) {
            int s0 = rfl(csr_src[j]);
            const uint4* eP = (const uint4*)(eab + ((size_t)(uint)j << 5));
            uint4 e00 = eP[0], e01 = eP[1];
            uint2 x0 = ldx(xlh, (uint)s0, laneoff);
            float p0 = logit_v(w, e00, e01, x0, xrv, a06, a04);
            #pragma unroll
            for (int off = 32; off >= 1; off >>= 1) p0 += __shfl_xor(p0, off);
            float q0 = exp2a(p0);
            denom += q0;
            ACC1(x0, q0)
        }
        float inv = 1.f / denom;
        ushort4 o;
        o.x = f2bf(fmaf(ac0, inv, bv.x));
        o.y = f2bf(fmaf(ac1, inv, bv.y));
        o.z = f2bf(fmaf(ac2, inv, bv.z));
        o.w = f2bf(fmaf(ac3, inv, bv.w));
        *(ushort4*)(out_bf + ((size_t)node << 8) + (lane << 2)) = o;
    }
}

// ---------------------------------------------------------------- layer-2 fused GAT: wave/node, halves = 2 edges (r7 form + exp2)
__global__ __launch_bounds__(256) void k_gat2(const float* __restrict__ xl,
                                              const float* __restrict__ xr,
                                              const _Float16* __restrict__ ea_h,
                                              const _Float16* __restrict__ We_h,
                                              const float* __restrict__ att,
                                              const float* __restrict__ bias,
                                              const int* __restrict__ rowptr,
                                              const int* __restrict__ csr_src,
                                              float* __restrict__ out, int n) {
    int tid = threadIdx.x;
    int lane = tid & 63;
    int sub = lane >> 5, c = lane & 31;
    int wave = (blockIdx.x * blockDim.x + tid) >> 6;
    int nwaves = (gridDim.x * blockDim.x) >> 6;
    const uint* Wp = (const uint*)We_h;
    uint w0 = Wp[c * 8 + 0], w1 = Wp[c * 8 + 1], w2 = Wp[c * 8 + 2], w3 = Wp[c * 8 + 3];
    uint w4 = Wp[c * 8 + 4], w5 = Wp[c * 8 + 5], w6 = Wp[c * 8 + 6], w7 = Wp[c * 8 + 7];
    const float L2E = 1.44269504088896f;
    float attc = att[c];
    float a06 = 0.6f * L2E * attc, a04 = 0.4f * L2E * attc;
    float bc = bias[c];

    for (int node = wave; node < n; node += nwaves) {
        float xrc = xr[((size_t)node << 5) + c];
        int beg = rowptr[node], end = rowptr[node + 1];
        float denom = 0.f, acc = 0.f;
        int j = beg;
        for (; j + 3 < end; j += 4) {
            int jA = j + sub, jB = j + 2 + sub;
            int sA = csr_src[jA], sB = csr_src[jB];
            const uint4* ePA = (const uint4*)((const char*)ea_h + ((uint)jA << 5));
            const uint4* ePB = (const uint4*)((const char*)ea_h + ((uint)jB << 5));
            uint4 a0 = ePA[0], a1 = ePA[1];
            uint4 b0 = ePB[0], b1 = ePB[1];
            float xlA = *(const float*)((const char*)xl + (((uint)sA << 7) + (c << 2)));
            float xlB = *(const float*)((const char*)xl + (((uint)sB << 7) + (c << 2)));
            float weA = dot2h(w7, a1.w, dot2h(w6, a1.z, dot2h(w5, a1.y, dot2h(w4, a1.x,
                        dot2h(w3, a0.w, dot2h(w2, a0.z, dot2h(w1, a0.y, dot2h(w0, a0.x, 0.f))))))));
            float weB = dot2h(w7, b1.w, dot2h(w6, b1.z, dot2h(w5, b1.y, dot2h(w4, b1.x,
                        dot2h(w3, b0.w, dot2h(w2, b0.z, dot2h(w1, b0.y, dot2h(w0, b0.x, 0.f))))))));
            float zA = xlA + xrc + weA;
            float zB = xlB + xrc + weB;
            float pA = fmaf(a06, zA, a04 * fabsf(zA));
            float pB = fmaf(a06, zB, a04 * fabsf(zB));
            #pragma unroll
            for (int off = 16; off >= 1; off >>= 1) {
                pA += __shfl_xor(pA, off);
                pB += __shfl_xor(pB, off);
            }
            float qA = exp2a(pA), qB = exp2a(pB);
            denom += qA + qB;
            acc = fmaf(qA, xlA, fmaf(qB, xlB, acc));
        }
        for (; j < end; j += 2) {
            int jj = j + sub;
            bool act = jj < end;
            int js = act ? jj : j;
            int s = csr_src[js];
            const uint4* eP = (const uint4*)((const char*)ea_h + ((uint)js << 5));
            uint4 e0 = eP[0], e1 = eP[1];
            float xlv = *(const float*)((const char*)xl + (((uint)s << 7) + (c << 2)));
            float we = dot2h(w7, e1.w, dot2h(w6, e1.z, dot2h(w5, e1.y, dot2h(w4, e1.x,
                       dot2h(w3, e0.w, dot2h(w2, e0.z, dot2h(w1, e0.y, dot2h(w0, e0.x, 0.f))))))));
            float z = xlv + xrc + we;
            float p = fmaf(a06, z, a04 * fabsf(z));
            #pragma unroll
            for (int off = 16; off >= 1; off >>= 1) p += __shfl_xor(p, off);
            float pe = act ? exp2a(p) : 0.f;
            denom += pe;
            acc = fmaf(pe, xlv, acc);
        }
        acc += __shfl_xor(acc, 32);
        denom += __shfl_xor(denom, 32);
        if (sub == 0) out[((size_t)node << 5) + c] = acc / denom + bc;
    }
}

// ---------------------------------------------------------------- mean over nodes
__global__ __launch_bounds__(256) void k_mean(const float* __restrict__ h2,
                                              float* __restrict__ out, int total, float invN) {
    __shared__ float red[H2];
    int tid = threadIdx.x;
    if (tid < H2) red[tid] = 0.f;
    __syncthreads();
    float part = 0.f;
    for (int idx = blockIdx.x * blockDim.x + tid; idx < total; idx += gridDim.x * blockDim.x)
        part += h2[idx];
    atomicAdd(&red[tid & 31], part);
    __syncthreads();
    if (tid < H2) atomicAdd(&out[tid], red[tid] * invN);
}

// ----------------------------------------------------------------
extern "C" void kernel_launch(void* const* d_in, const int* in_sizes, int n_in,
                              void* d_out, int out_size, void* d_ws, size_t ws_size,
                              hipStream_t stream) {
    const float* x   = (const float*)d_in[0];
    const int*   ei  = (const int*)d_in[1];
    const float* ea  = (const float*)d_in[2];
    const float* Wl1 = (const float*)d_in[3];
    const float* bl1 = (const float*)d_in[4];
    const float* Wr1 = (const float*)d_in[5];
    const float* br1 = (const float*)d_in[6];
    const float* We1 = (const float*)d_in[7];
    const float* at1 = (const float*)d_in[8];
    const float* bi1 = (const float*)d_in[9];
    const float* Wl2 = (const float*)d_in[10];
    const float* bl2 = (const float*)d_in[11];
    const float* Wr2 = (const float*)d_in[12];
    const float* br2 = (const float*)d_in[13];
    const float* We2 = (const float*)d_in[14];
    const float* at2 = (const float*)d_in[15];
    const float* bi2 = (const float*)d_in[16];
    float* out = (float*)d_out;

    const int N = N_NODES, E = N_EDGES, ET = N_EDGES + N_NODES;
    const int SCAN_CHUNK = (N + 255) / 256;

    size_t off = 0;
    auto carve = [&](size_t bytes) {
        void* p = (char*)d_ws + off;
        off += (bytes + 255) & ~(size_t)255;
        return p;
    };
    int*      counts  = (int*)carve((size_t)N * 4);
    int*      fill    = (int*)carve((size_t)N * 4);
    int*      rowptr  = (int*)carve((size_t)(N + 1) * 4);
    int*      partial = (int*)carve(256 * 4);
    int*      csr_src = (int*)carve((size_t)ET * 4);
    _Float16* ea_h    = (_Float16*)carve((size_t)ET * ED * 2);
    _Float16* We1_h   = (_Float16*)carve((size_t)H1 * ED * 2);
    _Float16* We2_h   = (_Float16*)carve((size_t)H2 * ED * 2);
    ushort*   x_bf    = (ushort*)carve((size_t)N * ND * 2);
    ushort*   wcat1   = (ushort*)carve((size_t)2 * H1 * ND * 2);
    ushort*   wcat2   = (ushort*)carve((size_t)2 * H2 * H1 * 2);
    _Float16* xl1h    = (_Float16*)carve((size_t)N * H1 * 2);
    _Float16* xr1h    = (_Float16*)carve((size_t)N * H1 * 2);
    ushort*   h1_bf   = (ushort*)carve((size_t)N * H1 * 2);
    float*    xl2     = (float*)carve((size_t)N * H2 * 4);
    float*    xr2     = (float*)carve((size_t)N * H2 * 4);
    float*    h2      = (float*)carve((size_t)N * H2 * 4);

    size_t zspan = (size_t)((char*)fill - (char*)counts) + (size_t)N * 4;
    hipMemsetAsync(counts, 0, zspan, stream);
    hipMemsetAsync(out, 0, (size_t)H2 * 4, stream);

    k_deg<<<(E + 255) / 256, 256, 0, stream>>>(ei, counts, E);
    k_scan1<<<256, 256, 0, stream>>>(counts, partial, N, SCAN_CHUNK);
    k_scan2<<<1, 256, 0, stream>>>(partial);
    k_scan3<<<256, 256, 0, stream>>>(counts, partial, rowptr, N, SCAN_CHUNK);
    k_fill_csr<<<(E + N + 255) / 256, 256, 0, stream>>>(ei, ea, rowptr, fill, csr_src, ea_h, E, N);
    k_loop_mean<<<1024, 256, 0, stream>>>(ea_h, rowptr, N);

    const int T4 = N_NODES * ND / 4;
    const int TS = 2 * H1 * ND + 2 * H2 * H1 + H1 * ED + H2 * ED;
    k_pack_all<<<(T4 + TS + 255) / 256, 256, 0, stream>>>(x, Wl1, Wr1, We1, Wl2, Wr2, We2,
                                                          x_bf, wcat1, wcat2, We1_h, We2_h);

    // layer 1: GEMM -> xl1h, xr1h (f16); fused GAT -> h1 (bf16)
    k_gemm_mfma<1, 1><<<dim3((N + 63) / 64, (2 * H1) / 64), 256, 0, stream>>>(
        x_bf, wcat1, bl1, br1, (void*)xl1h, (void*)xr1h, N, ND, H1);
    k_gat1<<<4096, 256, 0, stream>>>(xl1h, xr1h, ea_h, We1_h, at1, bi1,
                                     rowptr, csr_src, h1_bf, N);

    // layer 2
    k_gemm_mfma<0, 0><<<dim3((N + 63) / 64, (2 * H2) / 64), 256, 0, stream>>>(
        h1_bf, wcat2, bl2, br2, (void*)xl2, (void*)xr2, N, H1, H2);
    k_gat2<<<12500, 256, 0, stream>>>(xl2, xr2, ea_h, We2_h, at2, bi2,
                                      rowptr, csr_src, h2, N);

    k_mean<<<128, 256, 0, stream>>>(h2, out, N * H2, 1.0f / (float)N);
}